// Round 8
// baseline (690.084 us; speedup 1.0000x reference)
//
#include <hip/hip_runtime.h>
#include <stdint.h>

typedef __attribute__((ext_vector_type(8))) short short8;
typedef __attribute__((ext_vector_type(4))) float f32x4;
typedef __attribute__((ext_vector_type(4))) int i32x4;

#define DMODEL 768
#define HID    2048
#define MROWS  4096   // 2*2048 tokens

// B-spline constants: h = (4-(-4))/(16-3) = 8/13
#define KINVH  (13.0f/8.0f)
#define KNOT0  (-4.0f - 3.0f*(8.0f/13.0f))

// counted-vmcnt / raw-barrier primitives (T3+T4; sched_barrier per rule #18)
#define VM_WAIT(N) do { asm volatile("s_waitcnt vmcnt(" #N ")" ::: "memory"); \
                        __builtin_amdgcn_sched_barrier(0); } while (0)
#define LGKM0_BARRIER do { asm volatile("s_waitcnt lgkmcnt(0)" ::: "memory"); \
                           __builtin_amdgcn_sched_barrier(0); \
                           __builtin_amdgcn_s_barrier(); \
                           __builtin_amdgcn_sched_barrier(0); } while (0)

__device__ __forceinline__ unsigned short f2bf(float f) {
  unsigned int u = __float_as_uint(f);
  unsigned int r = (u + 0x7FFFu + ((u >> 16) & 1u)) >> 16;
  return (unsigned short)r;
}

// ---- weight f32 -> bf16 bits (4 elems/thread) ----
__global__ void __launch_bounds__(256) conv_bf16(const float* __restrict__ src,
                                                 unsigned short* __restrict__ dst,
                                                 int n4) {
  int i = blockIdx.x * 256 + threadIdx.x;
  if (i >= n4) return;
  float4 v = ((const float4*)src)[i];
  ushort4 o;
  o.x = f2bf(v.x); o.y = f2bf(v.y); o.z = f2bf(v.z); o.w = f2bf(v.w);
  ((ushort4*)dst)[i] = o;
}

// ---- split-K=2 reduce, in place: p[i] = p[i] + p[i+n4] ----
__global__ void __launch_bounds__(256) reduce2(float4* __restrict__ p, int n4) {
  int i = blockIdx.x * 256 + threadIdx.x;
  if (i >= n4) return;
  float4 a = p[i], b = p[i + n4];
  float4 r;
  r.x = a.x + b.x; r.y = a.y + b.y; r.z = a.z + b.z; r.w = a.w + b.w;
  p[i] = r;
}

// ---- split-K=4 reduce: out[i] = sum over 4 planes ----
__global__ void __launch_bounds__(256) reduce4(const float4* __restrict__ p,
                                               float4* __restrict__ out, int n4) {
  int i = blockIdx.x * 256 + threadIdx.x;
  if (i >= n4) return;
  float4 a = p[i], b = p[i + n4], c = p[i + 2 * n4], d = p[i + 3 * n4];
  float4 r;
  r.x = a.x + b.x + c.x + d.x;
  r.y = a.y + b.y + c.y + d.y;
  r.z = a.z + b.z + c.z + d.z;
  r.w = a.w + b.w + c.w + d.w;
  out[i] = r;
}

// ---- fused basis + GEMM, counted-vmcnt pipelined (T3+T4) ----
// C[n,o] = sum_{d,k} basis(X[n,d])_k * Wb[o, d*16+k]
// Tile: BM=64 x BN=256, BK=64. 4 waves in 1x4; wave tile 64x64 (FM=FN=4).
// KEY: B staging is WAVE-PRIVATE (wave w stages chunks wid*8+i and reads only
// rows [wid*64, wid*64+64)) -> B needs no barrier, only per-wave counted vmcnt.
// Only the 8KB A-tile (basis: wave-partitioned writes, all-wave reads) needs
// the per-step barrier -> raw s_barrier + lgkmcnt(0), NO vmcnt drain, so the
// next tile's 8 B-loads stay in flight across the barrier (the 2-phase-stall fix).
template<int DIN, int DOUT, int SPLITK>
__global__ void __launch_bounds__(256, 2)
kan_gemm(const float* __restrict__ X, const unsigned short* __restrict__ Wb,
         float* __restrict__ Out) {
  constexpr int BM  = 64;
  constexpr int BN  = 256;
  constexpr int NK  = (DIN * 16) / 64;
  constexpr int NKS = NK / SPLITK;
  constexpr int FM  = 4;
  constexpr int FN  = 4;
  __shared__ __align__(16) char smA[2][BM * 128];   // 2 x 8KB  (swizzled basis)
  __shared__ __align__(16) char smB[2][BN * 128];   // 2 x 32KB (swizzled via source)

  const int tid  = threadIdx.x;
  const int lane = tid & 63;
  const int wid  = tid >> 6;
  const int brow = blockIdx.x * BM;
  const int bcol = blockIdx.y * BN;
  const int kt0  = blockIdx.z * NKS;
  const int kt1  = kt0 + NKS;

  f32x4 acc[FM][FN];
#pragma unroll
  for (int m = 0; m < FM; ++m)
#pragma unroll
    for (int n = 0; n < FN; ++n) acc[m][n] = (f32x4){0.f, 0.f, 0.f, 0.f};

  int a_base[FM], a_sw[FM], b_base[FN], b_sw[FN];
#pragma unroll
  for (int m = 0; m < FM; ++m) {
    int row   = m * 16 + (lane & 15);
    a_base[m] = row * 128 + ((lane >> 4) * 16);
    a_sw[m]   = (row & 7) << 4;
  }
#pragma unroll
  for (int n = 0; n < FN; ++n) {
    int row   = wid * 64 + n * 16 + (lane & 15);
    b_base[n] = row * 128 + ((lane >> 4) * 16);
    b_sw[n]   = (row & 7) << 4;
  }

  const int br_ = tid >> 2;        // basis row
  const int bd_ = tid & 3;         // basis d-col within the 4-col step
  const float* xrow = X + (size_t)(brow + br_) * DIN + bd_;

  auto STAGE_B = [&](int kt, int buf) {
#pragma unroll
    for (int i = 0; i < 8; ++i) {
      const int c   = wid * 8 + i;              // wave-uniform chunk (8 rows = 1KB)
      const int row = c * 8 + (lane >> 3);
      const int gch = (lane & 7) ^ (lane >> 3);
      const unsigned short* src =
          Wb + (size_t)(bcol + row) * (DIN * 16) + kt * 64 + gch * 8;
      __builtin_amdgcn_global_load_lds(
          (const __attribute__((address_space(1))) unsigned int*)src,
          (__attribute__((address_space(3))) unsigned int*)(&smB[buf][0] + c * 1024),
          16, 0, 0);
    }
  };
  auto BASIS = [&](float xv, int buf) {
    char* smp = &smA[buf][0];
    float u  = (xv - KNOT0) * KINVH;
    float uf = floorf(u);
    int   jj = (int)uf;
    float t  = u - uf;
    float t2 = t * t, t3 = t2 * t;
    float p0 = (1.0f / 6.0f) * (1.0f - 3.0f * t + 3.0f * t2 - t3);
    float p1 = (1.0f / 6.0f) * (4.0f - 6.0f * t2 + 3.0f * t3);
    float p2 = (1.0f / 6.0f) * (1.0f + 3.0f * t + 3.0f * t2 - 3.0f * t3);
    float p3 = (1.0f / 6.0f) * t3;

    int base = br_ * 128 + bd_ * 32;
    int sw   = (br_ & 7) << 4;
    *(i32x4*)(smp + (base ^ sw))        = (i32x4){0, 0, 0, 0};
    *(i32x4*)(smp + ((base + 16) ^ sw)) = (i32x4){0, 0, 0, 0};
    unsigned short q0 = f2bf(p0), q1 = f2bf(p1), q2 = f2bf(p2), q3 = f2bf(p3);
    int k0 = jj - 3;
    if ((unsigned)(k0 + 0) < 16u) *(unsigned short*)(smp + ((base + (k0 + 0) * 2) ^ sw)) = q0;
    if ((unsigned)(k0 + 1) < 16u) *(unsigned short*)(smp + ((base + (k0 + 1) * 2) ^ sw)) = q1;
    if ((unsigned)(k0 + 2) < 16u) *(unsigned short*)(smp + ((base + (k0 + 2) * 2) ^ sw)) = q2;
    if ((unsigned)(k0 + 3) < 16u) *(unsigned short*)(smp + ((base + (k0 + 3) * 2) ^ sw)) = q3;
  };

  // ---- prologue: VMEM issue order = X(kt0)[1], B(kt0)[8], X(kt0+1)[1]
  float x0 = xrow[(size_t)kt0 * 4];
  STAGE_B(kt0, 0);
  int kn = (kt0 + 1 < kt1) ? kt0 + 1 : kt1 - 1;
  float xnext = xrow[(size_t)kn * 4];
  BASIS(x0, 0);                 // compiler waits vmcnt for x0 only (9 newer outstanding)
  LGKM0_BARRIER;

  int cur = 0;
  for (int kt = kt0; kt < kt1; ++kt) {
    const bool more = (kt + 1 < kt1);
    float xfar = 0.f;
    if (more) {
      STAGE_B(kt + 1, cur ^ 1);                     // 8 loads, stay in flight
      int kf = (kt + 2 < kt1) ? kt + 2 : kt1 - 1;
      xfar = xrow[(size_t)kf * 4];                  // +1 load
      VM_WAIT(9);    // waits B(kt)+X(kt+1); kt+1's 9 remain outstanding
    } else {
      VM_WAIT(0);    // last tile: drain
    }

    // kk=0 fragments (B wave-private: vmcnt above is the only sync needed)
    short8 a0[FM], b0[FN];
#pragma unroll
    for (int m = 0; m < FM; ++m)
      a0[m] = *(const short8*)(&smA[cur][0] + (a_base[m] ^ a_sw[m]));
#pragma unroll
    for (int n = 0; n < FN; ++n)
      b0[n] = *(const short8*)(&smB[cur][0] + (b_base[n] ^ b_sw[n]));

    // next A-tile basis into the other buffer (overlaps with kk0 MFMA)
    if (more) BASIS(xnext, cur ^ 1);

#pragma unroll
    for (int m = 0; m < FM; ++m)
#pragma unroll
      for (int n = 0; n < FN; ++n)
        acc[m][n] = __builtin_amdgcn_mfma_f32_16x16x32_bf16(a0[m], b0[n], acc[m][n], 0, 0, 0);

    // kk=1 fragments + MFMA
    short8 a1[FM], b1[FN];
#pragma unroll
    for (int m = 0; m < FM; ++m)
      a1[m] = *(const short8*)(&smA[cur][0] + ((a_base[m] + 64) ^ a_sw[m]));
#pragma unroll
    for (int n = 0; n < FN; ++n)
      b1[n] = *(const short8*)(&smB[cur][0] + ((b_base[n] + 64) ^ b_sw[n]));
#pragma unroll
    for (int m = 0; m < FM; ++m)
#pragma unroll
      for (int n = 0; n < FN; ++n)
        acc[m][n] = __builtin_amdgcn_mfma_f32_16x16x32_bf16(a1[m], b1[n], acc[m][n], 0, 0, 0);

    // A[nxt] writes visible to all waves; raw barrier WITHOUT vmcnt drain
    LGKM0_BARRIER;
    xnext = xfar;
    cur ^= 1;
  }

  // ---- epilogue: C/D layout col=lane&15, row=(lane>>4)*4+q
  float* outp = Out + (size_t)blockIdx.z * MROWS * DOUT;
#pragma unroll
  for (int m = 0; m < FM; ++m)
#pragma unroll
    for (int n = 0; n < FN; ++n)
#pragma unroll
      for (int q = 0; q < 4; ++q) {
        int grow = brow + m * 16 + (lane >> 4) * 4 + q;
        int gcol = bcol + wid * 64 + n * 16 + (lane & 15);
        outp[(size_t)grow * DOUT + gcol] = acc[m][n][q];
      }
}

extern "C" void kernel_launch(void* const* d_in, const int* in_sizes, int n_in,
                              void* d_out, int out_size, void* d_ws, size_t ws_size,
                              hipStream_t stream) {
  const float* x  = (const float*)d_in[0];   // (2,2048,768) f32 -> (4096,768)
  const float* w1 = (const float*)d_in[1];   // (2048,768,16) f32
  const float* w2 = (const float*)d_in[2];   // (768,2048,16) f32
  float* out = (float*)d_out;                // (4096,768) f32

  // ws timeline (128 MiB):
  //   [0, 48M)   : w1b (phase 1), then w2b (phase 2, after GEMM1)
  //   [48M, 80M) : GEMM1 partial plane 0 -> becomes h (f32) after reduce2
  //   [80M, 112M): GEMM1 partial plane 1 (dead after reduce2)
  //   [80M, 128M): GEMM2 partial planes 0..3 (overwrites plane 1)
  char* ws = (char*)d_ws;
  unsigned short* wgb   = (unsigned short*)ws;                  // 50,331,648 B
  float*          part1 = (float*)(ws + 50331648);              // 2 x 33,554,432 B
  float*          hbf   = part1;                                // alias: plane 0
  float*          part2 = (float*)(ws + 83886080);              // 4 x 12,582,912 B (end = 128MiB)

  const int n4 = (HID * DMODEL * 16) / 4;    // 6,291,456 float4 groups per weight

  // phase 1: layer 1
  conv_bf16<<<n4 / 256, 256, 0, stream>>>(w1, wgb, n4);
  kan_gemm<DMODEL, HID, 2>
      <<<dim3(MROWS / 64, HID / 256, 2), 256, 0, stream>>>(x, wgb, part1);
  const int hn4 = (MROWS * HID) / 4;         // 2,097,152
  reduce2<<<hn4 / 256, 256, 0, stream>>>((float4*)part1, hn4);   // h = plane0

  // phase 2: layer 2 (convert w2 now that w1b is dead)
  conv_bf16<<<n4 / 256, 256, 0, stream>>>(w2, wgb, n4);
  kan_gemm<HID, DMODEL, 4>
      <<<dim3(MROWS / 64, DMODEL / 256, 4), 256, 0, stream>>>(hbf, wgb, part2);
  const int rn4 = (MROWS * DMODEL) / 4;      // 786,432
  reduce4<<<rn4 / 256, 256, 0, stream>>>((const float4*)part2, (float4*)out, rn4);
}